// Round 1
// baseline (2898.513 us; speedup 1.0000x reference)
//
#include <hip/hip_runtime.h>
#include <math.h>

#define TT 256
#define HC 128
#define HB 64
#define NL 8

// ---- ws layout (floats) ----
// WgT  [8][128][64]  @ 0        : g_prev[c] * pw_in[i][o][c], transposed to [c][o]
// Pb   [8][64]       @ 65536    : sum_c b_prev[c]*pw_in[i][o][c]
// Pg   [8][64]       @ 66048    : sum_c g_prev[c]*pw_in[i][o][c]
// Gp   [8][128]      @ 66560    : g_prev[c] (identity for layer 0)
// Bp   [8][128]      @ 67584    : b_prev[c]
#define WS_WGT 0
#define WS_PB  65536
#define WS_PG  66048
#define WS_GP  66560
#define WS_BP  67584

__device__ __forceinline__ float fast_tanh(float x) {
    float e = __expf(2.f * fabsf(x));
    float r = 1.f - 2.f / (1.f + e);
    return copysignf(r, x);
}
__device__ __forceinline__ float fast_sig(float x) {
    return 1.f / (1.f + __expf(-x));
}

__global__ __launch_bounds__(128)
void tcn_setup(const float* __restrict__ pw_in, const float* __restrict__ gn_g,
               const float* __restrict__ gn_b, float* __restrict__ ws) {
    int i = blockIdx.x;      // layer
    int tid = threadIdx.x;   // 128 threads
    float* WgT = ws + WS_WGT;
    float* Pb  = ws + WS_PB;
    float* Pg  = ws + WS_PG;
    float* Gp  = ws + WS_GP;
    float* Bp  = ws + WS_BP;

    // per-channel prev-layer affine (identity for layer 0)
    float g = (i == 0) ? 1.f : gn_g[(i - 1) * HC + tid];
    float bb = (i == 0) ? 0.f : gn_b[(i - 1) * HC + tid];
    Gp[i * HC + tid] = g;
    Bp[i * HC + tid] = bb;
    // WgT[i][c=tid][o] = pw_in[i][o][c] * g
    for (int o = 0; o < HB; o++)
        WgT[(i * HC + tid) * HB + o] = pw_in[((size_t)i * HB + o) * HC + tid] * g;

    if (tid < HB) {
        float pb = 0.f, pg = 0.f;
        for (int c = 0; c < HC; c++) {
            float w = pw_in[((size_t)i * HB + tid) * HC + c];
            float gc = (i == 0) ? 1.f : gn_g[(i - 1) * HC + c];
            float bc = (i == 0) ? 0.f : gn_b[(i - 1) * HC + c];
            pb += bc * w;
            pg += gc * w;
        }
        Pb[i * HB + tid] = pb;
        Pg[i * HB + tid] = pg;
    }
}

// LDS layout (floats):
//   zp   [128][256]  channel-major, thread t owns column t  (32768)
//   halo [64][68]    u values for rows with (t&63)>=48      (4352)
//   sLast[8][128]    s_feat at t=255 per layer              (1024)
//   red  [16]        reduction scratch
//   hbuf [128], qbuf [128]
#define LDS_ZP    0
#define LDS_HALO  (128 * 256)
#define LDS_SLAST (LDS_HALO + 64 * 68)
#define LDS_RED   (LDS_SLAST + 8 * 128)
#define LDS_HBUF  (LDS_RED + 16)
#define LDS_QBUF  (LDS_HBUF + 128)
#define LDS_TOTAL (LDS_QBUF + 128)

__global__ __launch_bounds__(256, 1)
void tcn_main(const float* __restrict__ x, const float* __restrict__ in_w,
              const float* __restrict__ in_b, const float* __restrict__ dw_w,
              const float* __restrict__ pw_out, const float* __restrict__ skip_w,
              const float* __restrict__ ln_g, const float* __restrict__ ln_b,
              const float* __restrict__ h1_w, const float* __restrict__ h1_b,
              const float* __restrict__ h2_w, const float* __restrict__ h2_b,
              const float* __restrict__ ws, float* __restrict__ out) {
    extern __shared__ float lds[];
    float* zp    = lds + LDS_ZP;
    float* halo  = lds + LDS_HALO;
    float* sLast = lds + LDS_SLAST;
    float* red   = lds + LDS_RED;
    float* hbuf  = lds + LDS_HBUF;
    float* qbuf  = lds + LDS_QBUF;

    const float* WgT = ws + WS_WGT;
    const float* Pb  = ws + WS_PB;
    const float* Pg  = ws + WS_PG;
    const float* Gp  = ws + WS_GP;
    const float* Bp  = ws + WS_BP;

    const int t = threadIdx.x;     // time index, 0..255
    const int bn = blockIdx.x;     // sample
    const int b = bn >> 7, n = bn & 127;
    const int lane = t & 63;
    const int wv = t >> 6;

    // ---------- phase 0: input projection  zp[c][t] = x[b,t,n,:] @ in_w + in_b
    {
        const float* xp = x + (((size_t)b * TT + t) * 128 + n) * 16;
        float xr[16];
#pragma unroll
        for (int d = 0; d < 16; d++) xr[d] = xp[d];
        for (int c = 0; c < HC; c += 2) {
            float a0 = in_b[c], a1 = in_b[c + 1];
#pragma unroll
            for (int d = 0; d < 16; d++) {
                a0 += xr[d] * in_w[d * HC + c];
                a1 += xr[d] * in_w[d * HC + c + 1];
            }
            zp[c * TT + t] = a0;
            zp[(c + 1) * TT + t] = a1;
        }
    }

    float m_s = 0.f, r_s = 1.f;   // deferred groupnorm scalars (identity before layer 0)

    for (int L = 0; L < NL; L++) {
        const int dil = 1 << (L & 3);
        // ---------- u-phase: u[o] = r*(zp_row . WgT) + Pb[o] - m*r*Pg[o]
        float u[HB];
        {
            const float* W = WgT + (size_t)L * HC * HB;
#pragma unroll
            for (int o = 0; o < HB; o++) u[o] = 0.f;
            for (int c = 0; c < HC; c++) {
                float zr = zp[c * TT + t];
                const float* wrow = W + c * HB;
#pragma unroll
                for (int o = 0; o < HB; o++) u[o] += zr * wrow[o];
            }
            float mr = m_s * r_s;
            const float* pb = Pb + L * HB;
            const float* pg = Pg + L * HB;
#pragma unroll
            for (int o = 0; o < HB; o++) u[o] = r_s * u[o] + pb[o] - mr * pg[o];
        }
        // halo: rows with (t&63)>=48 publish u for cross-wave conv reads
        if (lane >= 48) {
            int hr = wv * 16 + (lane - 48);
#pragma unroll
            for (int o = 0; o < HB; o++) halo[hr * 68 + o] = u[o];
        }
        __syncthreads();

        // ---------- conv + gating: w_[c] = tanh(f[c]) * sigmoid(gate[c])
        float w_[HB];
        {
            const float* dwl = dw_w + (size_t)L * 128 * 3;
            const int d1 = dil, d2 = 2 * dil;
#pragma unroll
            for (int o = 0; o < 32; o++) {
                float um1 = __shfl_up(u[o], d1);
                float um2 = __shfl_up(u[o], d2);
                if (lane < d1) {
                    int tau = t - d1;
                    um1 = (tau < 0) ? 0.f : halo[((tau >> 6) * 16 + (tau & 63) - 48) * 68 + o];
                }
                if (lane < d2) {
                    int tau = t - d2;
                    um2 = (tau < 0) ? 0.f : halo[((tau >> 6) * 16 + (tau & 63) - 48) * 68 + o];
                }
                float f0 = um2 * dwl[(2 * o) * 3 + 0] + um1 * dwl[(2 * o) * 3 + 1] + u[o] * dwl[(2 * o) * 3 + 2];
                float f1 = um2 * dwl[(2 * o + 1) * 3 + 0] + um1 * dwl[(2 * o + 1) * 3 + 1] + u[o] * dwl[(2 * o + 1) * 3 + 2];
                w_[2 * o] = fast_tanh(f0);
                w_[2 * o + 1] = fast_tanh(f1);
            }
#pragma unroll
            for (int o = 32; o < HB; o++) {
                float um1 = __shfl_up(u[o], d1);
                float um2 = __shfl_up(u[o], d2);
                if (lane < d1) {
                    int tau = t - d1;
                    um1 = (tau < 0) ? 0.f : halo[((tau >> 6) * 16 + (tau & 63) - 48) * 68 + o];
                }
                if (lane < d2) {
                    int tau = t - d2;
                    um2 = (tau < 0) ? 0.f : halo[((tau >> 6) * 16 + (tau & 63) - 48) * 68 + o];
                }
                int c = 2 * (o - 32);
                float g0 = um2 * dwl[(64 + c) * 3 + 0] + um1 * dwl[(64 + c) * 3 + 1] + u[o] * dwl[(64 + c) * 3 + 2];
                float g1 = um2 * dwl[(64 + c + 1) * 3 + 0] + um1 * dwl[(64 + c + 1) * 3 + 1] + u[o] * dwl[(64 + c + 1) * 3 + 2];
                w_[c] *= fast_sig(g0);
                w_[c + 1] *= fast_sig(g1);
            }
        }

        // ---------- s-phase: s_feat, residual update (deferred GN applied), stats
        float s1 = 0.f, s2 = 0.f;
        const bool last = (L == NL - 1);
        if (!last || t == TT - 1) {
            const float* Po = pw_out + (size_t)L * HC * HB;
            const float mr = m_s * r_s;
            const float* gp = Gp + L * HC;
            const float* bp = Bp + L * HC;
            for (int c = 0; c < HC; c += 2) {
                float acc0 = 0.f, acc1 = 0.f;
                const float* p0 = Po + c * HB;
                const float* p1 = Po + (c + 1) * HB;
#pragma unroll
                for (int cc = 0; cc < HB; cc++) {
                    acc0 += w_[cc] * p0[cc];
                    acc1 += w_[cc] * p1[cc];
                }
                if (t == TT - 1) {
                    sLast[L * HC + c] = acc0;
                    sLast[L * HC + c + 1] = acc1;
                }
                if (!last) {
                    float g0 = gp[c], g1 = gp[c + 1];
                    float zo0 = zp[c * TT + t], zo1 = zp[(c + 1) * TT + t];
                    float zn0 = zo0 * (r_s * g0) + (bp[c] - mr * g0) + acc0;
                    float zn1 = zo1 * (r_s * g1) + (bp[c + 1] - mr * g1) + acc1;
                    zp[c * TT + t] = zn0;
                    zp[(c + 1) * TT + t] = zn1;
                    s1 += zn0 + zn1;
                    s2 += zn0 * zn0 + zn1 * zn1;
                }
            }
        }
        if (!last) {
#pragma unroll
            for (int off = 32; off; off >>= 1) {
                s1 += __shfl_xor(s1, off);
                s2 += __shfl_xor(s2, off);
            }
            if (lane == 0) { red[wv * 2] = s1; red[wv * 2 + 1] = s2; }
        }
        __syncthreads();
        if (!last) {
            float S1 = red[0] + red[2] + red[4] + red[6];
            float S2 = red[1] + red[3] + red[5] + red[7];
            float mu = S1 * (1.f / 32768.f);
            float var = S2 * (1.f / 32768.f) - mu * mu;
            m_s = mu;
            r_s = rsqrtf(var + 1e-5f);
        }
    }

    // ---------- head: h_last = sum_i skip_w[i] @ sLast[i]; LN; MLP
    float hl = 0.f;
    if (t < HC) {
        for (int i = 0; i < NL; i++) {
            const float4* swr = (const float4*)(skip_w + (((size_t)i * HC) + t) * HC);
            const float* sl = sLast + i * HC;
#pragma unroll 4
            for (int c4 = 0; c4 < 32; c4++) {
                float4 sw = swr[c4];
                hl += sw.x * sl[4 * c4] + sw.y * sl[4 * c4 + 1] + sw.z * sl[4 * c4 + 2] + sw.w * sl[4 * c4 + 3];
            }
        }
        hbuf[t] = hl;
    }
    __syncthreads();
    if (t < 64) {
        float v0 = hbuf[t], v1 = hbuf[t + 64];
        float a = v0 + v1, q = v0 * v0 + v1 * v1;
#pragma unroll
        for (int off = 32; off; off >>= 1) {
            a += __shfl_xor(a, off);
            q += __shfl_xor(q, off);
        }
        if (t == 0) {
            float mu = a * (1.f / 128.f);
            red[0] = mu;
            red[1] = rsqrtf(q * (1.f / 128.f) - mu * mu + 1e-5f);
        }
    }
    __syncthreads();
    {
        float mu = red[0], rs = red[1];
        if (t < HC) hbuf[t] = (hl - mu) * rs * ln_g[t] + ln_b[t];
    }
    __syncthreads();
    if (t < HC) {
        float q = h1_b[t];
        for (int c = 0; c < HC; c++) q += hbuf[c] * h1_w[c * HC + t];
        q = 0.5f * q * (1.f + erff(q * 0.70710678118654752f));
        qbuf[t] = q;
    }
    __syncthreads();
    if (t < 24) {
        float o = h2_b[t];
        for (int c = 0; c < HC; c++) o += qbuf[c] * h2_w[c * 24 + t];
        out[((size_t)b * 24 + t) * 128 + n] = o;
    }
}

extern "C" void kernel_launch(void* const* d_in, const int* in_sizes, int n_in,
                              void* d_out, int out_size, void* d_ws, size_t ws_size,
                              hipStream_t stream) {
    const float* x      = (const float*)d_in[0];
    const float* in_w   = (const float*)d_in[1];
    const float* in_b   = (const float*)d_in[2];
    const float* pw_in  = (const float*)d_in[3];
    const float* dw_w   = (const float*)d_in[4];
    const float* pw_out = (const float*)d_in[5];
    const float* gn_g   = (const float*)d_in[6];
    const float* gn_b   = (const float*)d_in[7];
    const float* skip_w = (const float*)d_in[8];
    const float* ln_g   = (const float*)d_in[9];
    const float* ln_b   = (const float*)d_in[10];
    const float* h1_w   = (const float*)d_in[11];
    const float* h1_b   = (const float*)d_in[12];
    const float* h2_w   = (const float*)d_in[13];
    const float* h2_b   = (const float*)d_in[14];
    float* out = (float*)d_out;
    float* ws  = (float*)d_ws;

    tcn_setup<<<NL, 128, 0, stream>>>(pw_in, gn_g, gn_b, ws);

    size_t smem = LDS_TOTAL * sizeof(float);
    static bool attr_done_unused = false; (void)attr_done_unused; // no guard semantics; call is idempotent
    hipFuncSetAttribute((const void*)tcn_main, hipFuncAttributeMaxDynamicSharedMemorySize, (int)smem);
    tcn_main<<<1024, 256, smem, stream>>>(x, in_w, in_b, dw_w, pw_out, skip_w,
                                          ln_g, ln_b, h1_w, h1_b, h2_w, h2_b, ws, out);
}